// Round 9
// baseline (503.425 us; speedup 1.0000x reference)
//
#include <hip/hip_runtime.h>
#include <hip/hip_bf16.h>
#include <stdint.h>

// SelfAttention: out = softmax((x Wq^T)(x Wk^T)^T / sqrt(D)) (x Wv^T)
// SEQ=8192, D=1024, fp32 in/out. All GEMMs bf16 MFMA (absmax ~2.4e-4).
// R18 = R17 (BK=32, 16KB LDS, XCD swizzle) with the bank-conflict fix.
// R17 evidence: XCD swizzle cut FETCH 510->100MB; S-GEMM 203->190us even
// WITH 16.8M bank conflicts from wrong rotation. BK=32 rows are 64B (16
// banks, 2 rows per 32-bank stripe); rotation must spread each 8-lane
// phase group over all 8 4-bank windows. (r>>2) gave only 4 -> 2x serial.
// Fix: rotate by (r>>1)&3. window(lr)=4*(lr&1)+((lq-(lr>>1))&3) is a
// bijection on lr=0..7 ({0,4,3,7,2,6,1,5}) and on lr=8..15. Staging slot
// stays thread-constant: sl=((tid&3)+((tid>>3)&3))&3. Read invariance:
// (r>>1)&3=(lr>>1)&3 (wm, mi*16 contribute multiples of 8 to r>>1).
// Keeps: compact q/k/v de-interleave, fused softmax epilogues (MODE1
// exp2 + atomic row sums, MODE2 1/l), split-K=2 PV, GROUP_M=8 grouping.
//
// Workspace (~230 MB): x_bf16 16 | Wcat 6 | q 16 | k 16 | v 16 | S 128 | pv 32
//                      | lsum 32KB

#define SEQ 8192
#define DMODEL 1024
#define LOG2E 1.44269504088896340736f
#define GROUP_M 8

typedef __bf16 bf16_t;
typedef __bf16 bf16x8 __attribute__((ext_vector_type(8)));
typedef float f32x4 __attribute__((ext_vector_type(4)));

// ---------------- fp32 -> bf16 convert ----------------
__global__ __launch_bounds__(256)
void convert_f32_bf16(const float* __restrict__ in, bf16_t* __restrict__ out, long n) {
    long i = ((long)blockIdx.x * 256 + threadIdx.x) * 4;
    if (i + 3 < n) {
        const float4 v = *(const float4*)(in + i);
        union { ushort4 u; bf16_t b[4]; } p;
        p.b[0] = (bf16_t)v.x; p.b[1] = (bf16_t)v.y;
        p.b[2] = (bf16_t)v.z; p.b[3] = (bf16_t)v.w;
        *(ushort4*)(out + i) = p.u;
    }
}

// ---------------- fp32 add: out += part ----------------
__global__ __launch_bounds__(256)
void add_f32(float* __restrict__ out, const float* __restrict__ part, long n) {
    long i = ((long)blockIdx.x * 256 + threadIdx.x) * 4;
    if (i + 3 < n) {
        float4 a = *(const float4*)(out + i);
        const float4 b = *(const float4*)(part + i);
        a.x += b.x; a.y += b.y; a.z += b.z; a.w += b.w;
        *(float4*)(out + i) = a;
    }
}

// ---------------- zero fp32 buffer ----------------
__global__ __launch_bounds__(256)
void zero_f32(float* __restrict__ p, int n) {
    int i = blockIdx.x * 256 + threadIdx.x;
    if (i < n) p[i] = 0.0f;
}

// ---------------- NT GEMM: C[M,N] = A[M,K] @ B[N,K]^T ----------------
// 128x128 tile, BK=32, 256 threads (4 waves, 2x2), each wave 64x64 via 4x4
// grid of mfma_f32_16x16x32_bf16, ONE K=32 step per staged tile.
// global_load_lds width-16 staging + (r>>1)-rotation swizzle (phase-bijective
// -> conflict-free b128 reads). XCD-chunked bid, then GROUP_M grouping.
// Split-K via grid.x = nsplit*nbm*nbn. De-interleave epilogue via plane/cshift.
// MODE 0: C = alpha*acc.
// MODE 1: C = exp2(alpha*acc) (bf16), atomic row-sums into lsum.
// MODE 2: C = acc / lsum[row]  (softmax normalization folded into PV).
template <typename OutT, int MODE>
__global__ __launch_bounds__(256, 3)
void gemm_nt(const bf16_t* __restrict__ A, const bf16_t* __restrict__ B,
             OutT* __restrict__ C0, OutT* __restrict__ C1,
             float* __restrict__ lsum,
             int M, int N, int Kps, int lda, int ldb, int ldc,
             long plane, int cshift, float alpha)
{
    __shared__ bf16_t As[128 * 32];   // 8KB
    __shared__ bf16_t Bs[128 * 32];   // 8KB

    const int tid  = threadIdx.x;
    const int wave = tid >> 6;
    const int lane = tid & 63;

    const int nbm = M >> 7, nbn = N >> 7;
    const int tiles = nbm * nbn;
    int bid = blockIdx.x;
    const int sid = bid / tiles;        // split-K id
    bid -= sid * tiles;
    const long kbase = (long)sid * Kps;
    OutT* __restrict__ C = sid ? C1 : C0;

    // XCD-chunked swizzle (bijective: tiles % 8 == 0 for all our launches):
    // consecutive hardware dispatches (same XCD) get contiguous tile ranges.
    const int cpx = tiles >> 3;
    bid = (bid & 7) * cpx + (bid >> 3);

    // grouped swizzle (GROUP_M row-tiles, col-major inside)
    const int per_group = GROUP_M * nbn;
    const int gid   = bid / per_group;
    const int rem   = bid - gid * per_group;
    const int first = gid * GROUP_M;
    const int gsz   = min(nbm - first, GROUP_M);
    const int bm    = first + rem % gsz;
    const int bn    = rem / gsz;
    const long row0 = (long)bm * 128;
    const long col0 = (long)bn * 128;

    const int wm = (wave >> 1) * 64;   // wave's 64x64 sub-tile
    const int wn = (wave & 1) * 64;
    const int lr = lane & 15;          // fragment non-K index
    const int lq = lane >> 4;          // k-chunk (chunk lq = k lq*8..+8)

    // --- staging: tile = 512 chunks of 16B; chunk c = i*256+tid (i=0,1);
    // row r=c>>2, phys slot p=c&3 holds global chunk l=(p+(r>>1))&3.
    // l is thread-constant: l = ((tid&3) + ((tid>>3)&3)) & 3.
    const int rt = tid >> 2;                         // row within 64-row block
    const int sl = ((tid & 3) + ((tid >> 3) & 3)) & 3;
    const bf16_t* pa = A + (row0 + rt) * (long)lda + kbase + sl * 8;
    const bf16_t* pb = B + (col0 + rt) * (long)ldb + kbase + sl * 8;

    // --- LDS read slot: chunk g=lq at row r lives at p0=(lq-((r>>1)&3))&3;
    // (r>>1)&3 == (lr>>1)&3 for all mi/ni (wm, mi*16 are multiples of 16).
    const int p0  = (lq - ((lr >> 1) & 3)) & 3;
    const int oA  = (wm + lr) * 32 + p0 * 8;
    const int oB  = (wn + lr) * 32 + p0 * 8;

    f32x4 acc[4][4] = {};

    for (int k0 = 0; k0 < Kps; k0 += 32) {
        // Stage A,B 128x32 tiles (512 x 16B chunks each).
        #pragma unroll
        for (int i = 0; i < 2; ++i) {
            const bf16_t* ga = pa + k0 + (long)i * 64 * lda;
            const bf16_t* gb = pb + k0 + (long)i * 64 * ldb;
            __builtin_amdgcn_global_load_lds(
                (const __attribute__((address_space(1))) uint32_t*)ga,
                (__attribute__((address_space(3))) uint32_t*)(As + (long)(i * 256 + tid) * 8),
                16, 0, 0);
            __builtin_amdgcn_global_load_lds(
                (const __attribute__((address_space(1))) uint32_t*)gb,
                (__attribute__((address_space(3))) uint32_t*)(Bs + (long)(i * 256 + tid) * 8),
                16, 0, 0);
        }
        __syncthreads();

        bf16x8 af[4], bfr[4];
        #pragma unroll
        for (int mi = 0; mi < 4; ++mi)
            af[mi] = *(const bf16x8*)(As + oA + mi * 512);
        #pragma unroll
        for (int ni = 0; ni < 4; ++ni)
            bfr[ni] = *(const bf16x8*)(Bs + oB + ni * 512);
        #pragma unroll
        for (int mi = 0; mi < 4; ++mi)
            #pragma unroll
            for (int ni = 0; ni < 4; ++ni)
                acc[mi][ni] = __builtin_amdgcn_mfma_f32_16x16x32_bf16(
                    af[mi], bfr[ni], acc[mi][ni], 0, 0, 0);
        __syncthreads();
    }

    // Epilogue: C/D layout col=lane&15, row=(lane>>4)*4+reg  [m89/m91 verified]
    OutT* __restrict__ Cb = C + (col0 >> cshift) * plane;
    const int ccol0 = (int)(col0 & (((long)1 << cshift) - 1));

    if (MODE == 1) {
        // P' = exp2(alpha*acc); row partial sums -> shfl over lr -> atomicAdd.
        #pragma unroll
        for (int mi = 0; mi < 4; ++mi)
            #pragma unroll
            for (int rg = 0; rg < 4; ++rg) {
                const long r = row0 + wm + mi * 16 + lq * 4 + rg;
                float part = 0.f;
                #pragma unroll
                for (int ni = 0; ni < 4; ++ni) {
                    const int c = ccol0 + wn + ni * 16 + lr;
                    const float e = exp2f(alpha * acc[mi][ni][rg]);
                    part += e;
                    Cb[r * (long)ldc + c] = (OutT)e;
                }
                part += __shfl_xor(part, 1);
                part += __shfl_xor(part, 2);
                part += __shfl_xor(part, 4);
                part += __shfl_xor(part, 8);
                if (lr == 0) atomicAdd(&lsum[r], part);
            }
    } else if (MODE == 2) {
        #pragma unroll
        for (int mi = 0; mi < 4; ++mi)
            #pragma unroll
            for (int rg = 0; rg < 4; ++rg) {
                const long r = row0 + wm + mi * 16 + lq * 4 + rg;
                const float inv = 1.0f / lsum[r];
                #pragma unroll
                for (int ni = 0; ni < 4; ++ni) {
                    const int c = ccol0 + wn + ni * 16 + lr;
                    Cb[r * (long)ldc + c] = (OutT)(acc[mi][ni][rg] * inv);
                }
            }
    } else {
        #pragma unroll
        for (int mi = 0; mi < 4; ++mi)
            #pragma unroll
            for (int ni = 0; ni < 4; ++ni)
                #pragma unroll
                for (int rg = 0; rg < 4; ++rg) {
                    const long r = row0 + wm + mi * 16 + lq * 4 + rg;
                    const int  c = ccol0 + wn + ni * 16 + lr;
                    Cb[r * (long)ldc + c] = (OutT)(alpha * acc[mi][ni][rg]);
                }
    }
}

// ---------------- bf16 transpose (strided in), v -> v^T ----------------
__global__ __launch_bounds__(256)
void transpose_bf16(const bf16_t* __restrict__ in, bf16_t* __restrict__ out,
                    int R, int ldin, int ldout)
{
    __shared__ bf16_t tile[32][33];
    const int tx = threadIdx.x & 31;
    const int ty = threadIdx.x >> 5;   // 0..7
    const int c0 = blockIdx.x * 32;
    const int r0 = blockIdx.y * 32;
    #pragma unroll
    for (int j = 0; j < 32; j += 8)
        tile[ty + j][tx] = in[(long)(r0 + ty + j) * ldin + c0 + tx];
    __syncthreads();
    #pragma unroll
    for (int j = 0; j < 32; j += 8)
        out[(long)(c0 + ty + j) * ldout + r0 + tx] = tile[tx][ty + j];
}

extern "C" void kernel_launch(void* const* d_in, const int* in_sizes, int n_in,
                              void* d_out, int out_size, void* d_ws, size_t ws_size,
                              hipStream_t stream)
{
    const float* x  = (const float*)d_in[0];
    const float* Wq = (const float*)d_in[1];
    const float* Wk = (const float*)d_in[2];
    const float* Wv = (const float*)d_in[3];
    float* out = (float*)d_out;

    char* ws = (char*)d_ws;
    const long XN = (long)SEQ * DMODEL;     // 8,388,608
    const long WN = (long)DMODEL * DMODEL;  // 1,048,576
    const long SN = (long)SEQ * SEQ;        // 67,108,864

    bf16_t* xb   = (bf16_t*)ws;                              // 16MB
    bf16_t* wcat = (bf16_t*)(ws + XN * 2);                   // 6MB [3072,1024]
    bf16_t* qb   = (bf16_t*)(ws + XN * 2 + WN * 6);          // 16MB compact
    bf16_t* kb   = qb + XN;                                  // 16MB compact
    bf16_t* vb   = qb + 2 * XN;                              // 16MB compact
    bf16_t* Sb   = (bf16_t*)(ws + XN * 2 + WN * 6 + XN * 6); // 128MB
    float*  pvp  = (float*)(ws + XN * 2 + WN * 6 + XN * 6 + SN * 2); // 32MB
    float*  lsum = (float*)(ws + XN * 2 + WN * 6 + XN * 6 + SN * 2 + XN * 4); // 32KB
    bf16_t* vtb  = xb;  // v^T overlays x_bf16 (x dead after QKV GEMM)

    const size_t base_need = (size_t)(XN * 2 + WN * 6 + XN * 6 + SN * 2);
    const bool use_split = ws_size >= base_need + XN * 4 + SEQ * 4;
    if (!use_split) lsum = (float*)(ws + base_need);  // reuse pvp slot

    convert_f32_bf16<<<(int)(XN / 4 / 256), 256, 0, stream>>>(x,  xb, XN);
    convert_f32_bf16<<<(int)(WN / 4 / 256), 256, 0, stream>>>(Wq, wcat,          WN);
    convert_f32_bf16<<<(int)(WN / 4 / 256), 256, 0, stream>>>(Wk, wcat + WN,     WN);
    convert_f32_bf16<<<(int)(WN / 4 / 256), 256, 0, stream>>>(Wv, wcat + 2 * WN, WN);
    zero_f32<<<SEQ / 256, 256, 0, stream>>>(lsum, SEQ);

    dim3 blk(256);
    // qkv = x @ Wcat^T, de-interleaved into compact q|k|v (plane=XN, cshift=10)
    gemm_nt<bf16_t, 0><<<(SEQ / 128) * (3 * DMODEL / 128), blk, 0, stream>>>(
        xb, wcat, qb, qb, nullptr, SEQ, 3 * DMODEL, DMODEL,
        DMODEL, DMODEL, DMODEL, XN, 10, 1.0f);

    // v^T for the PV GEMM (writes over dead x_bf16)
    transpose_bf16<<<dim3(DMODEL / 32, SEQ / 32), blk, 0, stream>>>(
        vb, vtb, SEQ, DMODEL, SEQ);

    // P' = exp2((q@k^T) * scale * log2e), bf16; row sums -> lsum (atomic)
    gemm_nt<bf16_t, 1><<<(SEQ / 128) * (SEQ / 128), blk, 0, stream>>>(
        qb, kb, Sb, Sb, lsum, SEQ, SEQ, DMODEL,
        DMODEL, DMODEL, SEQ, 0, 30, 0.03125f * LOG2E);

    // out = (P' @ v) / l  (PV epilogue applies 1/lsum[row]). Split-K=2 if ws.
    if (use_split) {
        gemm_nt<float, 2><<<2 * (SEQ / 128) * (DMODEL / 128), blk, 0, stream>>>(
            Sb, vtb, out, pvp, lsum, SEQ, DMODEL, SEQ / 2,
            SEQ, SEQ, DMODEL, 0, 30, 1.0f);
        add_f32<<<(int)(XN / 4 / 256), 256, 0, stream>>>(out, pvp, XN);
    } else {
        gemm_nt<float, 2><<<(SEQ / 128) * (DMODEL / 128), blk, 0, stream>>>(
            Sb, vtb, out, out, lsum, SEQ, DMODEL, SEQ,
            SEQ, SEQ, DMODEL, 0, 30, 1.0f);
    }
}

// Round 10
// 468.492 us; speedup vs baseline: 1.0746x; 1.0746x over previous
//
#include <hip/hip_runtime.h>
#include <hip/hip_bf16.h>
#include <stdint.h>

// SelfAttention: out = softmax((x Wq^T)(x Wk^T)^T / sqrt(D)) (x Wv^T)
// SEQ=8192, D=1024, fp32 in/out. All GEMMs bf16 MFMA (absmax ~2.4e-4).
// R19: heterogeneous composition of per-dispatch winners:
//  - S-GEMM  (MODE1): R18 gemm32  — 128² tile, BK=32, 16KB LDS, phase-
//    bijective (r>>1) rotation (0 conflicts), XCD chunking. 185.7us measured.
//  - QKV/PV (MODE0/2): R10 gemm256 — 256² tile, 512thr, BK=64, double-buffer
//    vmcnt(8) pipeline (474.9us-total config; QKV+PV+overhead=269.9us, best
//    measured) + XCD chunking added (tiles 384/128, %8==0 bijective).
// Ledger: R18 (BK=32 everywhere) total 503: S won (-17) but QKV/PV lost
// (+48 vs R10). Different GEMMs want different shapes; compose.
// Keeps: compact q/k/v de-interleave, fused softmax epilogues (MODE1
// exp2 + atomic row sums, MODE2 1/l), split-K=2 PV, GROUP_M=8 grouping.
//
// Workspace (~230 MB): x_bf16 16 | Wcat 6 | q 16 | k 16 | v 16 | S 128 | pv 32
//                      | lsum 32KB

#define SEQ 8192
#define DMODEL 1024
#define LOG2E 1.44269504088896340736f
#define GROUP_M 8

typedef __bf16 bf16_t;
typedef __bf16 bf16x8 __attribute__((ext_vector_type(8)));
typedef float f32x4 __attribute__((ext_vector_type(4)));

// ---------------- fp32 -> bf16 convert ----------------
__global__ __launch_bounds__(256)
void convert_f32_bf16(const float* __restrict__ in, bf16_t* __restrict__ out, long n) {
    long i = ((long)blockIdx.x * 256 + threadIdx.x) * 4;
    if (i + 3 < n) {
        const float4 v = *(const float4*)(in + i);
        union { ushort4 u; bf16_t b[4]; } p;
        p.b[0] = (bf16_t)v.x; p.b[1] = (bf16_t)v.y;
        p.b[2] = (bf16_t)v.z; p.b[3] = (bf16_t)v.w;
        *(ushort4*)(out + i) = p.u;
    }
}

// ---------------- fp32 add: out += part ----------------
__global__ __launch_bounds__(256)
void add_f32(float* __restrict__ out, const float* __restrict__ part, long n) {
    long i = ((long)blockIdx.x * 256 + threadIdx.x) * 4;
    if (i + 3 < n) {
        float4 a = *(const float4*)(out + i);
        const float4 b = *(const float4*)(part + i);
        a.x += b.x; a.y += b.y; a.z += b.z; a.w += b.w;
        *(float4*)(out + i) = a;
    }
}

// ---------------- zero fp32 buffer ----------------
__global__ __launch_bounds__(256)
void zero_f32(float* __restrict__ p, int n) {
    int i = blockIdx.x * 256 + threadIdx.x;
    if (i < n) p[i] = 0.0f;
}

// ======================================================================
// gemm256: 256x256 tile, BK=64, 512 threads (8 waves 2x4), per-wave 128x64
// via 8x4 grid of mfma_f32_16x16x32_bf16. R10 double-buffered pipeline:
// per K-tile: vmcnt(8) [t landed, t+1 in flight]; barrier; ds_read k0;
// MFMA mi0-3; ds_read k1; MFMA mi4-7; lgkm0+sched+barrier; STAGE(t+2,h0);
// MFMA k1 mi0-3; STAGE(t+2,h1); MFMA k1 mi4-7. Row-rotation LDS swizzle.
// Used for QKV (MODE0) and PV (MODE2).
// ======================================================================
template <typename OutT, int MODE>
__global__ __launch_bounds__(512, 2)
void gemm256(const bf16_t* __restrict__ A, const bf16_t* __restrict__ B,
             OutT* __restrict__ C0, OutT* __restrict__ C1,
             float* __restrict__ lsum,
             int M, int N, int Kps, int lda, int ldb, int ldc,
             long plane, int cshift, float alpha)
{
    __shared__ bf16_t As[2][256 * 64];
    __shared__ bf16_t Bs[2][256 * 64];

    const int tid  = threadIdx.x;
    const int wave = tid >> 6;
    const int lane = tid & 63;

    const int nbm = M >> 8, nbn = N >> 8;
    const int tiles = nbm * nbn;
    int bid = blockIdx.x;
    const int sid = bid / tiles;        // split-K id
    bid -= sid * tiles;
    const long kbase = (long)sid * Kps;
    OutT* __restrict__ C = sid ? C1 : C0;

    // XCD-chunked swizzle (bijective: tiles % 8 == 0 for our launches).
    const int cpx = tiles >> 3;
    bid = (bid & 7) * cpx + (bid >> 3);

    // grouped swizzle for L2 locality
    const int per_group = GROUP_M * nbn;
    const int gid   = bid / per_group;
    const int rem   = bid - gid * per_group;
    const int first = gid * GROUP_M;
    const int gsz   = min(nbm - first, GROUP_M);
    const int bm    = first + rem % gsz;
    const int bn    = rem / gsz;
    const long row0 = (long)bm * 256;
    const long col0 = (long)bn * 256;

    const int wm = (wave >> 2) * 128;  // wave's 128x64 sub-tile
    const int wn = (wave & 3) * 64;
    const int lr = lane & 15;          // fragment non-K index
    const int lq = lane >> 4;          // quad 0..3 -> k-chunk / row group

    // staging: rows rt=tid>>3 per 64-row block i; phys slot p=tid&7 holds
    // global chunk (p+r)&7 (rotation within the 128B row).
    const int rt = tid >> 3;
    const int sl = ((tid & 7) + rt) & 7;
    const bf16_t* pa = A + (row0 + rt) * (long)lda + kbase + sl * 8;
    const bf16_t* pb = B + (col0 + rt) * (long)ldb + kbase + sl * 8;

    // LDS read offsets: p = (chunk - row)&7; row&7 == lr&7.
    const int p0  = (lq - lr) & 7;          // ks=0 chunk = lq
    const int p1  = p0 ^ 4;                 // ks=1 chunk = 4+lq
    const int oA0 = (wm + lr) * 64 + p0 * 8;
    const int oA1 = (wm + lr) * 64 + p1 * 8;
    const int oB0 = (wn + lr) * 64 + p0 * 8;
    const int oB1 = (wn + lr) * 64 + p1 * 8;

    const int nt = Kps >> 6;

    f32x4 acc[8][4] = {};

#define STAGE2(kt, bsel, i0)                                                    \
    {                                                                           \
        _Pragma("unroll")                                                       \
        for (int ii = 0; ii < 2; ++ii) {                                        \
            const int i = (i0) + ii;                                            \
            const bf16_t* ga = pa + (long)(kt) * 64 + (long)i * 64 * lda;       \
            const bf16_t* gb = pb + (long)(kt) * 64 + (long)i * 64 * ldb;       \
            __builtin_amdgcn_global_load_lds(                                   \
                (const __attribute__((address_space(1))) uint32_t*)ga,          \
                (__attribute__((address_space(3))) uint32_t*)(As[bsel] + i * 4096 + tid * 8), \
                16, 0, 0);                                                      \
            __builtin_amdgcn_global_load_lds(                                   \
                (const __attribute__((address_space(1))) uint32_t*)gb,          \
                (__attribute__((address_space(3))) uint32_t*)(Bs[bsel] + i * 4096 + tid * 8), \
                16, 0, 0);                                                      \
        }                                                                       \
    }

    // prologue: stage tiles 0 and 1
    STAGE2(0, 0, 0); STAGE2(0, 0, 2);
    if (nt > 1) { STAGE2(1, 1, 0); STAGE2(1, 1, 2); }

    int cur = 0;
    for (int t = 0; t < nt; ++t) {
        const bf16_t* as = As[cur];
        const bf16_t* bs = Bs[cur];

        // tile t's 8 loads done (tile t+1's 8 may remain in flight)
        if (t + 1 < nt) { asm volatile("s_waitcnt vmcnt(8)" ::: "memory"); }
        else            { asm volatile("s_waitcnt vmcnt(0)" ::: "memory"); }
        __builtin_amdgcn_s_barrier();

        bf16x8 a0[8], b0[4], a1[8], b1[4];
        #pragma unroll
        for (int mi = 0; mi < 8; ++mi)
            a0[mi] = *(const bf16x8*)(as + oA0 + mi * 1024);
        #pragma unroll
        for (int ni = 0; ni < 4; ++ni)
            b0[ni] = *(const bf16x8*)(bs + oB0 + ni * 1024);

        __builtin_amdgcn_s_setprio(1);
        #pragma unroll
        for (int mi = 0; mi < 4; ++mi)
            #pragma unroll
            for (int ni = 0; ni < 4; ++ni)
                acc[mi][ni] = __builtin_amdgcn_mfma_f32_16x16x32_bf16(
                    a0[mi], b0[ni], acc[mi][ni], 0, 0, 0);
        __builtin_amdgcn_s_setprio(0);

        #pragma unroll
        for (int mi = 0; mi < 8; ++mi)
            a1[mi] = *(const bf16x8*)(as + oA1 + mi * 1024);
        #pragma unroll
        for (int ni = 0; ni < 4; ++ni)
            b1[ni] = *(const bf16x8*)(bs + oB1 + ni * 1024);

        __builtin_amdgcn_s_setprio(1);
        #pragma unroll
        for (int mi = 4; mi < 8; ++mi)
            #pragma unroll
            for (int ni = 0; ni < 4; ++ni)
                acc[mi][ni] = __builtin_amdgcn_mfma_f32_16x16x32_bf16(
                    a0[mi], b0[ni], acc[mi][ni], 0, 0, 0);
        __builtin_amdgcn_s_setprio(0);

        // all LDS reads of buf cur retired in every wave -> safe to DMA t+2.
        asm volatile("s_waitcnt lgkmcnt(0)" ::: "memory");
        __builtin_amdgcn_sched_barrier(0);
        __builtin_amdgcn_s_barrier();

        if (t + 2 < nt) STAGE2(t + 2, cur, 0);

        __builtin_amdgcn_s_setprio(1);
        #pragma unroll
        for (int mi = 0; mi < 4; ++mi)
            #pragma unroll
            for (int ni = 0; ni < 4; ++ni)
                acc[mi][ni] = __builtin_amdgcn_mfma_f32_16x16x32_bf16(
                    a1[mi], b1[ni], acc[mi][ni], 0, 0, 0);
        __builtin_amdgcn_s_setprio(0);

        if (t + 2 < nt) STAGE2(t + 2, cur, 2);

        __builtin_amdgcn_s_setprio(1);
        #pragma unroll
        for (int mi = 4; mi < 8; ++mi)
            #pragma unroll
            for (int ni = 0; ni < 4; ++ni)
                acc[mi][ni] = __builtin_amdgcn_mfma_f32_16x16x32_bf16(
                    a1[mi], b1[ni], acc[mi][ni], 0, 0, 0);
        __builtin_amdgcn_s_setprio(0);

        cur ^= 1;
    }
#undef STAGE2

    // Epilogue: C/D layout col=lane&15, row=(lane>>4)*4+reg  [m89/m91]
    OutT* __restrict__ Cb = C + (col0 >> cshift) * plane;
    const int ccol0 = (int)(col0 & (((long)1 << cshift) - 1));

    if (MODE == 1) {
        #pragma unroll
        for (int mi = 0; mi < 8; ++mi)
            #pragma unroll
            for (int rg = 0; rg < 4; ++rg) {
                const long r = row0 + wm + mi * 16 + lq * 4 + rg;
                float part = 0.f;
                #pragma unroll
                for (int ni = 0; ni < 4; ++ni) {
                    const int cc = ccol0 + wn + ni * 16 + lr;
                    const float e = exp2f(alpha * acc[mi][ni][rg]);
                    part += e;
                    Cb[r * (long)ldc + cc] = (OutT)e;
                }
                part += __shfl_xor(part, 1);
                part += __shfl_xor(part, 2);
                part += __shfl_xor(part, 4);
                part += __shfl_xor(part, 8);
                if (lr == 0) atomicAdd(&lsum[r], part);
            }
    } else if (MODE == 2) {
        #pragma unroll
        for (int mi = 0; mi < 8; ++mi)
            #pragma unroll
            for (int rg = 0; rg < 4; ++rg) {
                const long r = row0 + wm + mi * 16 + lq * 4 + rg;
                const float inv = 1.0f / lsum[r];
                #pragma unroll
                for (int ni = 0; ni < 4; ++ni) {
                    const int cc = ccol0 + wn + ni * 16 + lr;
                    Cb[r * (long)ldc + cc] = (OutT)(acc[mi][ni][rg] * inv);
                }
            }
    } else {
        #pragma unroll
        for (int mi = 0; mi < 8; ++mi)
            #pragma unroll
            for (int ni = 0; ni < 4; ++ni)
                #pragma unroll
                for (int rg = 0; rg < 4; ++rg) {
                    const long r = row0 + wm + mi * 16 + lq * 4 + rg;
                    const int  cc = ccol0 + wn + ni * 16 + lr;
                    Cb[r * (long)ldc + cc] = (OutT)(alpha * acc[mi][ni][rg]);
                }
    }
}

// ======================================================================
// gemm32: 128x128 tile, BK=32, 256 threads (4 waves 2x2), wave 64x64 via
// 4x4 grid of mfma_f32_16x16x32_bf16. 16KB LDS -> high occupancy.
// (r>>1)-rotation swizzle: phase-bijective -> 0 bank conflicts (R18).
// XCD chunking + GROUP_M. Used for the S-GEMM (MODE1).
// ======================================================================
template <typename OutT, int MODE>
__global__ __launch_bounds__(256, 3)
void gemm32(const bf16_t* __restrict__ A, const bf16_t* __restrict__ B,
            OutT* __restrict__ C0, OutT* __restrict__ C1,
            float* __restrict__ lsum,
            int M, int N, int Kps, int lda, int ldb, int ldc,
            long plane, int cshift, float alpha)
{
    __shared__ bf16_t As[128 * 32];   // 8KB
    __shared__ bf16_t Bs[128 * 32];   // 8KB

    const int tid  = threadIdx.x;
    const int wave = tid >> 6;
    const int lane = tid & 63;

    const int nbm = M >> 7, nbn = N >> 7;
    const int tiles = nbm * nbn;
    int bid = blockIdx.x;
    const int sid = bid / tiles;
    bid -= sid * tiles;
    const long kbase = (long)sid * Kps;
    OutT* __restrict__ C = sid ? C1 : C0;

    const int cpx = tiles >> 3;
    bid = (bid & 7) * cpx + (bid >> 3);

    const int per_group = GROUP_M * nbn;
    const int gid   = bid / per_group;
    const int rem   = bid - gid * per_group;
    const int first = gid * GROUP_M;
    const int gsz   = min(nbm - first, GROUP_M);
    const int bm    = first + rem % gsz;
    const int bn    = rem / gsz;
    const long row0 = (long)bm * 128;
    const long col0 = (long)bn * 128;

    const int wm = (wave >> 1) * 64;
    const int wn = (wave & 1) * 64;
    const int lr = lane & 15;
    const int lq = lane >> 4;

    // staging: chunk c=i*256+tid; row r=c>>2, phys slot p=c&3 holds global
    // chunk l=(p+(r>>1))&3; thread-constant l=((tid&3)+((tid>>3)&3))&3.
    const int rt = tid >> 2;
    const int sl = ((tid & 3) + ((tid >> 3) & 3)) & 3;
    const bf16_t* pa = A + (row0 + rt) * (long)lda + kbase + sl * 8;
    const bf16_t* pb = B + (col0 + rt) * (long)ldb + kbase + sl * 8;

    // read slot: p0=(lq-((r>>1)&3))&3; (r>>1)&3 == (lr>>1)&3.
    const int p0  = (lq - ((lr >> 1) & 3)) & 3;
    const int oA  = (wm + lr) * 32 + p0 * 8;
    const int oB  = (wn + lr) * 32 + p0 * 8;

    f32x4 acc[4][4] = {};

    for (int k0 = 0; k0 < Kps; k0 += 32) {
        #pragma unroll
        for (int i = 0; i < 2; ++i) {
            const bf16_t* ga = pa + k0 + (long)i * 64 * lda;
            const bf16_t* gb = pb + k0 + (long)i * 64 * ldb;
            __builtin_amdgcn_global_load_lds(
                (const __attribute__((address_space(1))) uint32_t*)ga,
                (__attribute__((address_space(3))) uint32_t*)(As + (long)(i * 256 + tid) * 8),
                16, 0, 0);
            __builtin_amdgcn_global_load_lds(
                (const __attribute__((address_space(1))) uint32_t*)gb,
                (__attribute__((address_space(3))) uint32_t*)(Bs + (long)(i * 256 + tid) * 8),
                16, 0, 0);
        }
        __syncthreads();

        bf16x8 af[4], bfr[4];
        #pragma unroll
        for (int mi = 0; mi < 4; ++mi)
            af[mi] = *(const bf16x8*)(As + oA + mi * 512);
        #pragma unroll
        for (int ni = 0; ni < 4; ++ni)
            bfr[ni] = *(const bf16x8*)(Bs + oB + ni * 512);
        #pragma unroll
        for (int mi = 0; mi < 4; ++mi)
            #pragma unroll
            for (int ni = 0; ni < 4; ++ni)
                acc[mi][ni] = __builtin_amdgcn_mfma_f32_16x16x32_bf16(
                    af[mi], bfr[ni], acc[mi][ni], 0, 0, 0);
        __syncthreads();
    }

    OutT* __restrict__ Cb = C + (col0 >> cshift) * plane;
    const int ccol0 = (int)(col0 & (((long)1 << cshift) - 1));

    if (MODE == 1) {
        #pragma unroll
        for (int mi = 0; mi < 4; ++mi)
            #pragma unroll
            for (int rg = 0; rg < 4; ++rg) {
                const long r = row0 + wm + mi * 16 + lq * 4 + rg;
                float part = 0.f;
                #pragma unroll
                for (int ni = 0; ni < 4; ++ni) {
                    const int c = ccol0 + wn + ni * 16 + lr;
                    const float e = exp2f(alpha * acc[mi][ni][rg]);
                    part += e;
                    Cb[r * (long)ldc + c] = (OutT)e;
                }
                part += __shfl_xor(part, 1);
                part += __shfl_xor(part, 2);
                part += __shfl_xor(part, 4);
                part += __shfl_xor(part, 8);
                if (lr == 0) atomicAdd(&lsum[r], part);
            }
    } else if (MODE == 2) {
        #pragma unroll
        for (int mi = 0; mi < 4; ++mi)
            #pragma unroll
            for (int rg = 0; rg < 4; ++rg) {
                const long r = row0 + wm + mi * 16 + lq * 4 + rg;
                const float inv = 1.0f / lsum[r];
                #pragma unroll
                for (int ni = 0; ni < 4; ++ni) {
                    const int c = ccol0 + wn + ni * 16 + lr;
                    Cb[r * (long)ldc + c] = (OutT)(acc[mi][ni][rg] * inv);
                }
            }
    } else {
        #pragma unroll
        for (int mi = 0; mi < 4; ++mi)
            #pragma unroll
            for (int ni = 0; ni < 4; ++ni)
                #pragma unroll
                for (int rg = 0; rg < 4; ++rg) {
                    const long r = row0 + wm + mi * 16 + lq * 4 + rg;
                    const int  c = ccol0 + wn + ni * 16 + lr;
                    Cb[r * (long)ldc + c] = (OutT)(alpha * acc[mi][ni][rg]);
                }
    }
}

// ---------------- bf16 transpose (strided in), v -> v^T ----------------
__global__ __launch_bounds__(256)
void transpose_bf16(const bf16_t* __restrict__ in, bf16_t* __restrict__ out,
                    int R, int ldin, int ldout)
{
    __shared__ bf16_t tile[32][33];
    const int tx = threadIdx.x & 31;
    const int ty = threadIdx.x >> 5;   // 0..7
    const int c0 = blockIdx.x * 32;
    const int r0 = blockIdx.y * 32;
    #pragma unroll
    for (int j = 0; j < 32; j += 8)
        tile[ty + j][tx] = in[(long)(r0 + ty + j) * ldin + c0 + tx];
    __syncthreads();
    #pragma unroll
    for (int j = 0; j < 32; j += 8)
        out[(long)(c0 + ty + j) * ldout + r0 + tx] = tile[tx][ty + j];
}

extern "C" void kernel_launch(void* const* d_in, const int* in_sizes, int n_in,
                              void* d_out, int out_size, void* d_ws, size_t ws_size,
                              hipStream_t stream)
{
    const float* x  = (const float*)d_in[0];
    const float* Wq = (const float*)d_in[1];
    const float* Wk = (const float*)d_in[2];
    const float* Wv = (const float*)d_in[3];
    float* out = (float*)d_out;

    char* ws = (char*)d_ws;
    const long XN = (long)SEQ * DMODEL;     // 8,388,608
    const long WN = (long)DMODEL * DMODEL;  // 1,048,576
    const long SN = (long)SEQ * SEQ;        // 67,108,864

    bf16_t* xb   = (bf16_t*)ws;                              // 16MB
    bf16_t* wcat = (bf16_t*)(ws + XN * 2);                   // 6MB [3072,1024]
    bf16_t* qb   = (bf16_t*)(ws + XN * 2 + WN * 6);          // 16MB compact
    bf16_t* kb   = qb + XN;                                  // 16MB compact
    bf16_t* vb   = qb + 2 * XN;                              // 16MB compact
    bf16_t* Sb   = (bf16_t*)(ws + XN * 2 + WN * 6 + XN * 6); // 128MB
    float*  pvp  = (float*)(ws + XN * 2 + WN * 6 + XN * 6 + SN * 2); // 32MB
    float*  lsum = (float*)(ws + XN * 2 + WN * 6 + XN * 6 + SN * 2 + XN * 4); // 32KB
    bf16_t* vtb  = xb;  // v^T overlays x_bf16 (x dead after QKV GEMM)

    const size_t base_need = (size_t)(XN * 2 + WN * 6 + XN * 6 + SN * 2);
    const bool use_split = ws_size >= base_need + XN * 4 + SEQ * 4;
    if (!use_split) lsum = (float*)(ws + base_need);  // reuse pvp slot

    convert_f32_bf16<<<(int)(XN / 4 / 256), 256, 0, stream>>>(x,  xb, XN);
    convert_f32_bf16<<<(int)(WN / 4 / 256), 256, 0, stream>>>(Wq, wcat,          WN);
    convert_f32_bf16<<<(int)(WN / 4 / 256), 256, 0, stream>>>(Wk, wcat + WN,     WN);
    convert_f32_bf16<<<(int)(WN / 4 / 256), 256, 0, stream>>>(Wv, wcat + 2 * WN, WN);
    zero_f32<<<SEQ / 256, 256, 0, stream>>>(lsum, SEQ);

    dim3 blk256(256);
    dim3 blk512(512);
    // qkv = x @ Wcat^T, de-interleaved into compact q|k|v (plane=XN, cshift=10)
    gemm256<bf16_t, 0><<<(SEQ / 256) * (3 * DMODEL / 256), blk512, 0, stream>>>(
        xb, wcat, qb, qb, nullptr, SEQ, 3 * DMODEL, DMODEL,
        DMODEL, DMODEL, DMODEL, XN, 10, 1.0f);

    // v^T for the PV GEMM (writes over dead x_bf16)
    transpose_bf16<<<dim3(DMODEL / 32, SEQ / 32), blk256, 0, stream>>>(
        vb, vtb, SEQ, DMODEL, SEQ);

    // P' = exp2((q@k^T) * scale * log2e), bf16; row sums -> lsum (atomic)
    gemm32<bf16_t, 1><<<(SEQ / 128) * (SEQ / 128), blk256, 0, stream>>>(
        qb, kb, Sb, Sb, lsum, SEQ, SEQ, DMODEL,
        DMODEL, DMODEL, SEQ, 0, 30, 0.03125f * LOG2E);

    // out = (P' @ v) / l  (PV epilogue applies 1/lsum[row]). Split-K=2 if ws.
    if (use_split) {
        gemm256<float, 2><<<2 * (SEQ / 256) * (DMODEL / 256), blk512, 0, stream>>>(
            Sb, vtb, out, pvp, lsum, SEQ, DMODEL, SEQ / 2,
            SEQ, SEQ, DMODEL, 0, 30, 1.0f);
        add_f32<<<(int)(XN / 4 / 256), 256, 0, stream>>>(out, pvp, XN);
    } else {
        gemm256<float, 2><<<(SEQ / 256) * (DMODEL / 256), blk512, 0, stream>>>(
            Sb, vtb, out, out, lsum, SEQ, DMODEL, SEQ,
            SEQ, SEQ, DMODEL, 0, 30, 1.0f);
    }
}

// Round 11
// 457.252 us; speedup vs baseline: 1.1010x; 1.0246x over previous
//
#include <hip/hip_runtime.h>
#include <hip/hip_bf16.h>
#include <stdint.h>

// SelfAttention: out = softmax((x Wq^T)(x Wk^T)^T / sqrt(D)) (x Wv^T)
// SEQ=8192, D=1024, fp32 in/out. All GEMMs bf16 MFMA (absmax ~2.4e-4).
// R20: R19 composition + new gemm_hn (128x256 tile) for QKV/PV.
// Ledger insight: tile choice was trading occupancy vs operand re-read
// traffic (PV-256²: nbn=4 traffic-optimal but 1 blk/CU; PV-128²: 4 blk/CU
// but 2x S-traffic). 128x256 gets both: BM=128 -> PV 512 blocks (2/CU,
// 48KB LDS caps at 3), BN=256 -> nbn=4 (S re-read 512MB, same as 256²).
// Inner loop = R9's verified single-buffered BK=64 loop verbatim; only
// staging counts (A:2,B:4 chunks/thread @512thr) and 2x4 wave grid differ.
//  - S-GEMM (MODE1): gemm32 (BK=32, 16KB LDS, phase-bijective rotation,
//    0 conflicts, XCD chunk) — 185us measured, unchanged.
//  - QKV (MODE0) & PV (MODE2): gemm_hn, XCD chunk (768/256 tiles, %8==0).
// Keeps: compact q/k/v de-interleave, fused softmax epilogues, split-K=2 PV,
// GROUP_M=8 grouping.
//
// Workspace (~230 MB): x_bf16 16 | Wcat 6 | q 16 | k 16 | v 16 | S 128 | pv 32
//                      | lsum 32KB

#define SEQ 8192
#define DMODEL 1024
#define LOG2E 1.44269504088896340736f
#define GROUP_M 8

typedef __bf16 bf16_t;
typedef __bf16 bf16x8 __attribute__((ext_vector_type(8)));
typedef float f32x4 __attribute__((ext_vector_type(4)));

// ---------------- fp32 -> bf16 convert ----------------
__global__ __launch_bounds__(256)
void convert_f32_bf16(const float* __restrict__ in, bf16_t* __restrict__ out, long n) {
    long i = ((long)blockIdx.x * 256 + threadIdx.x) * 4;
    if (i + 3 < n) {
        const float4 v = *(const float4*)(in + i);
        union { ushort4 u; bf16_t b[4]; } p;
        p.b[0] = (bf16_t)v.x; p.b[1] = (bf16_t)v.y;
        p.b[2] = (bf16_t)v.z; p.b[3] = (bf16_t)v.w;
        *(ushort4*)(out + i) = p.u;
    }
}

// ---------------- fp32 add: out += part ----------------
__global__ __launch_bounds__(256)
void add_f32(float* __restrict__ out, const float* __restrict__ part, long n) {
    long i = ((long)blockIdx.x * 256 + threadIdx.x) * 4;
    if (i + 3 < n) {
        float4 a = *(const float4*)(out + i);
        const float4 b = *(const float4*)(part + i);
        a.x += b.x; a.y += b.y; a.z += b.z; a.w += b.w;
        *(float4*)(out + i) = a;
    }
}

// ---------------- zero fp32 buffer ----------------
__global__ __launch_bounds__(256)
void zero_f32(float* __restrict__ p, int n) {
    int i = blockIdx.x * 256 + threadIdx.x;
    if (i < n) p[i] = 0.0f;
}

// ======================================================================
// gemm_hn: 128x256 tile, BK=64, 512 threads (8 waves as 2x4), per-wave
// 64x64 via 4x4 grid of mfma_f32_16x16x32_bf16 (R9's register shape).
// Single-buffered R9 loop: stage(A:2+B:4 gload_lds/thread) -> syncthreads
// -> 2 x {8 frag ds_reads + 16 MFMA} -> syncthreads. Row-rotation swizzle
// (128B rows, (p+r)&7) -> 0 bank conflicts. XCD chunk + GROUP_M.
// MODE 0: C = alpha*acc. MODE 2: C = acc / lsum[row].
// ======================================================================
template <typename OutT, int MODE>
__global__ __launch_bounds__(512, 2)
void gemm_hn(const bf16_t* __restrict__ A, const bf16_t* __restrict__ B,
             OutT* __restrict__ C0, OutT* __restrict__ C1,
             float* __restrict__ lsum,
             int M, int N, int Kps, int lda, int ldb, int ldc,
             long plane, int cshift, float alpha)
{
    __shared__ bf16_t As[128 * 64];   // 16KB
    __shared__ bf16_t Bs[256 * 64];   // 32KB

    const int tid  = threadIdx.x;
    const int wave = tid >> 6;
    const int lane = tid & 63;

    const int nbm = M >> 7, nbn = N >> 8;
    const int tiles = nbm * nbn;
    int bid = blockIdx.x;
    const int sid = bid / tiles;        // split-K id
    bid -= sid * tiles;
    const long kbase = (long)sid * Kps;
    OutT* __restrict__ C = sid ? C1 : C0;

    // XCD-chunked swizzle (bijective: tiles % 8 == 0 for our launches).
    const int cpx = tiles >> 3;
    bid = (bid & 7) * cpx + (bid >> 3);

    // grouped swizzle (GROUP_M row-tiles, col-major inside)
    const int per_group = GROUP_M * nbn;
    const int gid   = bid / per_group;
    const int rem   = bid - gid * per_group;
    const int first = gid * GROUP_M;
    const int gsz   = min(nbm - first, GROUP_M);
    const int bm    = first + rem % gsz;
    const int bn    = rem / gsz;
    const long row0 = (long)bm * 128;
    const long col0 = (long)bn * 256;

    const int wm = (wave >> 2) * 64;   // 2 row-waves
    const int wn = (wave & 3) * 64;    // 4 col-waves
    const int lr = lane & 15;          // fragment non-K index
    const int lq = lane >> 4;          // quad 0..3 -> k-chunk / row group

    // staging: rows rt=tid>>3 per 64-row block i; phys slot p=tid&7 holds
    // global chunk (p+r)&7 (rotation within the 128B row); r&7 == rt&7.
    const int rt = tid >> 3;
    const int sl = ((tid & 7) + rt) & 7;
    const bf16_t* pa = A + (row0 + rt) * (long)lda + kbase + sl * 8;
    const bf16_t* pb = B + (col0 + rt) * (long)ldb + kbase + sl * 8;

    // LDS read slot: chunk g at row r lives at p=(g-r)&7; r&7 == lr&7.
    const int p0  = (lq - lr) & 7;          // t=0 chunk = lq
    const int p1  = p0 ^ 4;                 // t=1 chunk = 4+lq
    const int oA0 = (wm + lr) * 64 + p0 * 8;
    const int oA1 = (wm + lr) * 64 + p1 * 8;
    const int oB0 = (wn + lr) * 64 + p0 * 8;
    const int oB1 = (wn + lr) * 64 + p1 * 8;

    f32x4 acc[4][4] = {};

    for (int k0 = 0; k0 < Kps; k0 += 64) {
        // Stage A (128x64: 2 chunks/thread) + B (256x64: 4 chunks/thread).
        #pragma unroll
        for (int i = 0; i < 2; ++i) {
            const bf16_t* ga = pa + k0 + (long)i * 64 * lda;
            __builtin_amdgcn_global_load_lds(
                (const __attribute__((address_space(1))) uint32_t*)ga,
                (__attribute__((address_space(3))) uint32_t*)(As + i * 4096 + tid * 8),
                16, 0, 0);
        }
        #pragma unroll
        for (int i = 0; i < 4; ++i) {
            const bf16_t* gb = pb + k0 + (long)i * 64 * ldb;
            __builtin_amdgcn_global_load_lds(
                (const __attribute__((address_space(1))) uint32_t*)gb,
                (__attribute__((address_space(3))) uint32_t*)(Bs + i * 4096 + tid * 8),
                16, 0, 0);
        }
        __syncthreads();

        #pragma unroll
        for (int t = 0; t < 2; ++t) {   // two K=32 MFMA steps per staged tile
            bf16x8 af[4], bfr[4];
            const int oA = t ? oA1 : oA0;
            const int oB = t ? oB1 : oB0;
            #pragma unroll
            for (int mi = 0; mi < 4; ++mi)
                af[mi] = *(const bf16x8*)(As + oA + mi * 1024);
            #pragma unroll
            for (int ni = 0; ni < 4; ++ni)
                bfr[ni] = *(const bf16x8*)(Bs + oB + ni * 1024);
            #pragma unroll
            for (int mi = 0; mi < 4; ++mi)
                #pragma unroll
                for (int ni = 0; ni < 4; ++ni)
                    acc[mi][ni] = __builtin_amdgcn_mfma_f32_16x16x32_bf16(
                        af[mi], bfr[ni], acc[mi][ni], 0, 0, 0);
        }
        __syncthreads();
    }

    // Epilogue: C/D layout col=lane&15, row=(lane>>4)*4+reg  [m89/m91]
    OutT* __restrict__ Cb = C + (col0 >> cshift) * plane;
    const int ccol0 = (int)(col0 & (((long)1 << cshift) - 1));

    if (MODE == 2) {
        #pragma unroll
        for (int mi = 0; mi < 4; ++mi)
            #pragma unroll
            for (int rg = 0; rg < 4; ++rg) {
                const long r = row0 + wm + mi * 16 + lq * 4 + rg;
                const float inv = 1.0f / lsum[r];
                #pragma unroll
                for (int ni = 0; ni < 4; ++ni) {
                    const int c = ccol0 + wn + ni * 16 + lr;
                    Cb[r * (long)ldc + c] = (OutT)(acc[mi][ni][rg] * inv);
                }
            }
    } else {
        #pragma unroll
        for (int mi = 0; mi < 4; ++mi)
            #pragma unroll
            for (int ni = 0; ni < 4; ++ni)
                #pragma unroll
                for (int rg = 0; rg < 4; ++rg) {
                    const long r = row0 + wm + mi * 16 + lq * 4 + rg;
                    const int  c = ccol0 + wn + ni * 16 + lr;
                    Cb[r * (long)ldc + c] = (OutT)(alpha * acc[mi][ni][rg]);
                }
    }
}

// ======================================================================
// gemm32: 128x128 tile, BK=32, 256 threads (4 waves 2x2), wave 64x64 via
// 4x4 grid of mfma_f32_16x16x32_bf16. 16KB LDS -> high occupancy.
// (r>>1)-rotation swizzle: phase-bijective -> 0 bank conflicts (R18).
// XCD chunking + GROUP_M. Used for the S-GEMM (MODE1).
// ======================================================================
template <typename OutT, int MODE>
__global__ __launch_bounds__(256, 3)
void gemm32(const bf16_t* __restrict__ A, const bf16_t* __restrict__ B,
            OutT* __restrict__ C0, OutT* __restrict__ C1,
            float* __restrict__ lsum,
            int M, int N, int Kps, int lda, int ldb, int ldc,
            long plane, int cshift, float alpha)
{
    __shared__ bf16_t As[128 * 32];   // 8KB
    __shared__ bf16_t Bs[128 * 32];   // 8KB

    const int tid  = threadIdx.x;
    const int wave = tid >> 6;
    const int lane = tid & 63;

    const int nbm = M >> 7, nbn = N >> 7;
    const int tiles = nbm * nbn;
    int bid = blockIdx.x;
    const int sid = bid / tiles;
    bid -= sid * tiles;
    const long kbase = (long)sid * Kps;
    OutT* __restrict__ C = sid ? C1 : C0;

    const int cpx = tiles >> 3;
    bid = (bid & 7) * cpx + (bid >> 3);

    const int per_group = GROUP_M * nbn;
    const int gid   = bid / per_group;
    const int rem   = bid - gid * per_group;
    const int first = gid * GROUP_M;
    const int gsz   = min(nbm - first, GROUP_M);
    const int bm    = first + rem % gsz;
    const int bn    = rem / gsz;
    const long row0 = (long)bm * 128;
    const long col0 = (long)bn * 128;

    const int wm = (wave >> 1) * 64;
    const int wn = (wave & 1) * 64;
    const int lr = lane & 15;
    const int lq = lane >> 4;

    // staging: chunk c=i*256+tid; row r=c>>2, phys slot p=c&3 holds global
    // chunk l=(p+(r>>1))&3; thread-constant l=((tid&3)+((tid>>3)&3))&3.
    const int rt = tid >> 2;
    const int sl = ((tid & 3) + ((tid >> 3) & 3)) & 3;
    const bf16_t* pa = A + (row0 + rt) * (long)lda + kbase + sl * 8;
    const bf16_t* pb = B + (col0 + rt) * (long)ldb + kbase + sl * 8;

    // read slot: p0=(lq-((r>>1)&3))&3; (r>>1)&3 == (lr>>1)&3.
    const int p0  = (lq - ((lr >> 1) & 3)) & 3;
    const int oA  = (wm + lr) * 32 + p0 * 8;
    const int oB  = (wn + lr) * 32 + p0 * 8;

    f32x4 acc[4][4] = {};

    for (int k0 = 0; k0 < Kps; k0 += 32) {
        #pragma unroll
        for (int i = 0; i < 2; ++i) {
            const bf16_t* ga = pa + k0 + (long)i * 64 * lda;
            const bf16_t* gb = pb + k0 + (long)i * 64 * ldb;
            __builtin_amdgcn_global_load_lds(
                (const __attribute__((address_space(1))) uint32_t*)ga,
                (__attribute__((address_space(3))) uint32_t*)(As + (long)(i * 256 + tid) * 8),
                16, 0, 0);
            __builtin_amdgcn_global_load_lds(
                (const __attribute__((address_space(1))) uint32_t*)gb,
                (__attribute__((address_space(3))) uint32_t*)(Bs + (long)(i * 256 + tid) * 8),
                16, 0, 0);
        }
        __syncthreads();

        bf16x8 af[4], bfr[4];
        #pragma unroll
        for (int mi = 0; mi < 4; ++mi)
            af[mi] = *(const bf16x8*)(As + oA + mi * 512);
        #pragma unroll
        for (int ni = 0; ni < 4; ++ni)
            bfr[ni] = *(const bf16x8*)(Bs + oB + ni * 512);
        #pragma unroll
        for (int mi = 0; mi < 4; ++mi)
            #pragma unroll
            for (int ni = 0; ni < 4; ++ni)
                acc[mi][ni] = __builtin_amdgcn_mfma_f32_16x16x32_bf16(
                    af[mi], bfr[ni], acc[mi][ni], 0, 0, 0);
        __syncthreads();
    }

    OutT* __restrict__ Cb = C + (col0 >> cshift) * plane;
    const int ccol0 = (int)(col0 & (((long)1 << cshift) - 1));

    if (MODE == 1) {
        #pragma unroll
        for (int mi = 0; mi < 4; ++mi)
            #pragma unroll
            for (int rg = 0; rg < 4; ++rg) {
                const long r = row0 + wm + mi * 16 + lq * 4 + rg;
                float part = 0.f;
                #pragma unroll
                for (int ni = 0; ni < 4; ++ni) {
                    const int c = ccol0 + wn + ni * 16 + lr;
                    const float e = exp2f(alpha * acc[mi][ni][rg]);
                    part += e;
                    Cb[r * (long)ldc + c] = (OutT)e;
                }
                part += __shfl_xor(part, 1);
                part += __shfl_xor(part, 2);
                part += __shfl_xor(part, 4);
                part += __shfl_xor(part, 8);
                if (lr == 0) atomicAdd(&lsum[r], part);
            }
    } else if (MODE == 2) {
        #pragma unroll
        for (int mi = 0; mi < 4; ++mi)
            #pragma unroll
            for (int rg = 0; rg < 4; ++rg) {
                const long r = row0 + wm + mi * 16 + lq * 4 + rg;
                const float inv = 1.0f / lsum[r];
                #pragma unroll
                for (int ni = 0; ni < 4; ++ni) {
                    const int c = ccol0 + wn + ni * 16 + lr;
                    Cb[r * (long)ldc + c] = (OutT)(acc[mi][ni][rg] * inv);
                }
            }
    } else {
        #pragma unroll
        for (int mi = 0; mi < 4; ++mi)
            #pragma unroll
            for (int ni = 0; ni < 4; ++ni)
                #pragma unroll
                for (int rg = 0; rg < 4; ++rg) {
                    const long r = row0 + wm + mi * 16 + lq * 4 + rg;
                    const int  c = ccol0 + wn + ni * 16 + lr;
                    Cb[r * (long)ldc + c] = (OutT)(alpha * acc[mi][ni][rg]);
                }
    }
}

// ---------------- bf16 transpose (strided in), v -> v^T ----------------
__global__ __launch_bounds__(256)
void transpose_bf16(const bf16_t* __restrict__ in, bf16_t* __restrict__ out,
                    int R, int ldin, int ldout)
{
    __shared__ bf16_t tile[32][33];
    const int tx = threadIdx.x & 31;
    const int ty = threadIdx.x >> 5;   // 0..7
    const int c0 = blockIdx.x * 32;
    const int r0 = blockIdx.y * 32;
    #pragma unroll
    for (int j = 0; j < 32; j += 8)
        tile[ty + j][tx] = in[(long)(r0 + ty + j) * ldin + c0 + tx];
    __syncthreads();
    #pragma unroll
    for (int j = 0; j < 32; j += 8)
        out[(long)(c0 + ty + j) * ldout + r0 + tx] = tile[tx][ty + j];
}

extern "C" void kernel_launch(void* const* d_in, const int* in_sizes, int n_in,
                              void* d_out, int out_size, void* d_ws, size_t ws_size,
                              hipStream_t stream)
{
    const float* x  = (const float*)d_in[0];
    const float* Wq = (const float*)d_in[1];
    const float* Wk = (const float*)d_in[2];
    const float* Wv = (const float*)d_in[3];
    float* out = (float*)d_out;

    char* ws = (char*)d_ws;
    const long XN = (long)SEQ * DMODEL;     // 8,388,608
    const long WN = (long)DMODEL * DMODEL;  // 1,048,576
    const long SN = (long)SEQ * SEQ;        // 67,108,864

    bf16_t* xb   = (bf16_t*)ws;                              // 16MB
    bf16_t* wcat = (bf16_t*)(ws + XN * 2);                   // 6MB [3072,1024]
    bf16_t* qb   = (bf16_t*)(ws + XN * 2 + WN * 6);          // 16MB compact
    bf16_t* kb   = qb + XN;                                  // 16MB compact
    bf16_t* vb   = qb + 2 * XN;                              // 16MB compact
    bf16_t* Sb   = (bf16_t*)(ws + XN * 2 + WN * 6 + XN * 6); // 128MB
    float*  pvp  = (float*)(ws + XN * 2 + WN * 6 + XN * 6 + SN * 2); // 32MB
    float*  lsum = (float*)(ws + XN * 2 + WN * 6 + XN * 6 + SN * 2 + XN * 4); // 32KB
    bf16_t* vtb  = xb;  // v^T overlays x_bf16 (x dead after QKV GEMM)

    const size_t base_need = (size_t)(XN * 2 + WN * 6 + XN * 6 + SN * 2);
    const bool use_split = ws_size >= base_need + XN * 4 + SEQ * 4;
    if (!use_split) lsum = (float*)(ws + base_need);  // reuse pvp slot

    convert_f32_bf16<<<(int)(XN / 4 / 256), 256, 0, stream>>>(x,  xb, XN);
    convert_f32_bf16<<<(int)(WN / 4 / 256), 256, 0, stream>>>(Wq, wcat,          WN);
    convert_f32_bf16<<<(int)(WN / 4 / 256), 256, 0, stream>>>(Wk, wcat + WN,     WN);
    convert_f32_bf16<<<(int)(WN / 4 / 256), 256, 0, stream>>>(Wv, wcat + 2 * WN, WN);
    zero_f32<<<SEQ / 256, 256, 0, stream>>>(lsum, SEQ);

    dim3 blk256(256);
    dim3 blk512(512);
    // qkv = x @ Wcat^T, de-interleaved into compact q|k|v (plane=XN, cshift=10)
    gemm_hn<bf16_t, 0><<<(SEQ / 128) * (3 * DMODEL / 256), blk512, 0, stream>>>(
        xb, wcat, qb, qb, nullptr, SEQ, 3 * DMODEL, DMODEL,
        DMODEL, DMODEL, DMODEL, XN, 10, 1.0f);

    // v^T for the PV GEMM (writes over dead x_bf16)
    transpose_bf16<<<dim3(DMODEL / 32, SEQ / 32), blk256, 0, stream>>>(
        vb, vtb, SEQ, DMODEL, SEQ);

    // P' = exp2((q@k^T) * scale * log2e), bf16; row sums -> lsum (atomic)
    gemm32<bf16_t, 1><<<(SEQ / 128) * (SEQ / 128), blk256, 0, stream>>>(
        qb, kb, Sb, Sb, lsum, SEQ, SEQ, DMODEL,
        DMODEL, DMODEL, SEQ, 0, 30, 0.03125f * LOG2E);

    // out = (P' @ v) / l  (PV epilogue applies 1/lsum[row]). Split-K=2 if ws.
    if (use_split) {
        gemm_hn<float, 2><<<2 * (SEQ / 128) * (DMODEL / 256), blk512, 0, stream>>>(
            Sb, vtb, out, pvp, lsum, SEQ, DMODEL, SEQ / 2,
            SEQ, SEQ, DMODEL, 0, 30, 1.0f);
        add_f32<<<(int)(XN / 4 / 256), 256, 0, stream>>>(out, pvp, XN);
    } else {
        gemm_hn<float, 2><<<(SEQ / 128) * (DMODEL / 256), blk512, 0, stream>>>(
            Sb, vtb, out, out, lsum, SEQ, DMODEL, SEQ,
            SEQ, SEQ, DMODEL, 0, 30, 1.0f);
    }
}